// Round 7
// baseline (285.981 us; speedup 1.0000x reference)
//
#include <hip/hip_runtime.h>
#include <hip/hip_bf16.h>
#include <math.h>

#define B 32
#define P 100
#define N 1000
#define D 128

constexpr float SQRT_D_INV = 1.0f / 11.313708498984761f;
constexpr float CLIPV = 10.0f;

__device__ __forceinline__ void fma4(float4& a, float s, const float4& b) {
    a.x = fmaf(s, b.x, a.x);
    a.y = fmaf(s, b.y, a.y);
    a.z = fmaf(s, b.z, a.z);
    a.w = fmaf(s, b.w, a.w);
}

// ---------------------------------------------------------------------------
// K0: transpose all 4 weight matrices (128x128) for coalesced streaming.
// ---------------------------------------------------------------------------
__global__ void transpose_w4(const float* __restrict__ Wk,
                             const float* __restrict__ Wv,
                             const float* __restrict__ Wqf,
                             const float* __restrict__ Wql,
                             float* __restrict__ wkT,
                             float* __restrict__ wvT,
                             float* __restrict__ wqfT,
                             float* __restrict__ wqlT) {
    const int e = blockIdx.x;
    const int d = threadIdx.x;
    wkT[e * D + d]  = Wk[d * D + e];
    wvT[e * D + d]  = Wv[d * D + e];
    wqfT[e * D + d] = Wqf[d * D + e];
    wqlT[e * D + d] = Wql[d * D + e];
}

// ---------------------------------------------------------------------------
// K0b: transpose nodes -> nodesT[b][e][n].
// ---------------------------------------------------------------------------
#define TT 64
__global__ __launch_bounds__(256) void transpose_nodes(
        const float* __restrict__ nodes, float* __restrict__ nodesT) {
    __shared__ float sh[TT][D + 1];
    const int ntiles = (N + TT - 1) / TT;
    const int b  = blockIdx.x / ntiles;
    const int n0 = (blockIdx.x % ntiles) * TT;
    const int t = threadIdx.x;
    const int rows = min(TT, N - n0);

    const float4* src = (const float4*)(nodes + ((long)b * N + n0) * D);
    for (int i = t; i < rows * (D / 4); i += 256) {
        int r = i >> 5, c = i & 31;
        float4 v = src[(long)r * (D / 4) + c];
        sh[r][c * 4 + 0] = v.x; sh[r][c * 4 + 1] = v.y;
        sh[r][c * 4 + 2] = v.z; sh[r][c * 4 + 3] = v.w;
    }
    __syncthreads();

    const int nl = t & 63;
    const int eg = t >> 6;
    if (nl < rows) {
        #pragma unroll
        for (int k = 0; k < 32; ++k) {
            int e = eg * 32 + k;
            nodesT[((long)b * D + e) * N + n0 + nl] = sh[nl][e];
        }
    }
}

// ---------------------------------------------------------------------------
// K1: ek = exp(nodes @ WkT), ekv = ek * (nodes @ WvT)
// ---------------------------------------------------------------------------
#define R1 32
__global__ __launch_bounds__(256, 2) void kv_kernel(
        const float* __restrict__ nodes,
        const float* __restrict__ wkT,
        const float* __restrict__ wvT,
        float* __restrict__ ek,
        float* __restrict__ ekv) {
    __shared__ float sh[R1][D];
    const int t = threadIdx.x;
    const int dq = t & 31;
    const int rl = t >> 5;
    const long row0 = (long)blockIdx.x * R1;

    const float4* src = (const float4*)(nodes + row0 * D);
    float4* dst = (float4*)(&sh[0][0]);
    #pragma unroll
    for (int i = 0; i < (R1 * D / 4) / 256; ++i)
        dst[t + i * 256] = src[t + i * 256];
    __syncthreads();

    float4 ka[4], va[4];
    #pragma unroll
    for (int rr = 0; rr < 4; ++rr) {
        ka[rr] = make_float4(0.f, 0.f, 0.f, 0.f);
        va[rr] = make_float4(0.f, 0.f, 0.f, 0.f);
    }

    const float* wkp = wkT + dq * 4;
    const float* wvp = wvT + dq * 4;
    #pragma unroll 4
    for (int e0 = 0; e0 < D; e0 += 4) {
        float4 wk4[4], wv4[4];
        #pragma unroll
        for (int ee = 0; ee < 4; ++ee) {
            wk4[ee] = *(const float4*)(wkp + (e0 + ee) * D);
            wv4[ee] = *(const float4*)(wvp + (e0 + ee) * D);
        }
        #pragma unroll
        for (int rr = 0; rr < 4; ++rr) {
            float4 s4 = *(const float4*)(&sh[rl * 4 + rr][e0]);
            fma4(ka[rr], s4.x, wk4[0]); fma4(ka[rr], s4.y, wk4[1]);
            fma4(ka[rr], s4.z, wk4[2]); fma4(ka[rr], s4.w, wk4[3]);
            fma4(va[rr], s4.x, wv4[0]); fma4(va[rr], s4.y, wv4[1]);
            fma4(va[rr], s4.z, wv4[2]); fma4(va[rr], s4.w, wv4[3]);
        }
    }

    #pragma unroll
    for (int rr = 0; rr < 4; ++rr) {
        long row = row0 + rl * 4 + rr;
        float4 e4;
        e4.x = __expf(ka[rr].x); e4.y = __expf(ka[rr].y);
        e4.z = __expf(ka[rr].z); e4.w = __expf(ka[rr].w);
        float4 ev;
        ev.x = e4.x * va[rr].x; ev.y = e4.y * va[rr].y;
        ev.z = e4.z * va[rr].z; ev.w = e4.w * va[rr].w;
        *(float4*)(ek + row * D + dq * 4) = e4;
        *(float4*)(ekv + row * D + dq * 4) = ev;
    }
}

// ---------------------------------------------------------------------------
// K2: qsig = sigmoid(q1 @ Wqf^T + qlast @ Wql^T), coalesced weight streams.
// ---------------------------------------------------------------------------
#define R2 16
__global__ __launch_bounds__(256, 2) void q_kernel(
        const float* __restrict__ q1,
        const float* __restrict__ qlast,
        const float* __restrict__ wqfT,
        const float* __restrict__ wqlT,
        float* __restrict__ qsig) {
    __shared__ float sh1[R2][D];
    __shared__ float sh2[R2][D];
    const int t = threadIdx.x;
    const int dq = t & 31;
    const int rl = t >> 5;
    const long row0 = (long)blockIdx.x * R2;

    const float4* s1 = (const float4*)(q1 + row0 * D);
    const float4* s2 = (const float4*)(qlast + row0 * D);
    float4* d1 = (float4*)(&sh1[0][0]);
    float4* d2 = (float4*)(&sh2[0][0]);
    #pragma unroll
    for (int i = 0; i < (R2 * D / 4) / 256; ++i) {
        d1[t + i * 256] = s1[t + i * 256];
        d2[t + i * 256] = s2[t + i * 256];
    }
    __syncthreads();

    float4 acc[2];
    acc[0] = make_float4(0.f, 0.f, 0.f, 0.f);
    acc[1] = make_float4(0.f, 0.f, 0.f, 0.f);

    const float* wfp = wqfT + dq * 4;
    const float* wlp = wqlT + dq * 4;
    #pragma unroll 4
    for (int e0 = 0; e0 < D; e0 += 4) {
        float4 wf4[4], wl4[4];
        #pragma unroll
        for (int ee = 0; ee < 4; ++ee) {
            wf4[ee] = *(const float4*)(wfp + (e0 + ee) * D);
            wl4[ee] = *(const float4*)(wlp + (e0 + ee) * D);
        }
        #pragma unroll
        for (int rr = 0; rr < 2; ++rr) {
            float4 a4 = *(const float4*)(&sh1[rl * 2 + rr][e0]);
            float4 b4 = *(const float4*)(&sh2[rl * 2 + rr][e0]);
            fma4(acc[rr], a4.x, wf4[0]); fma4(acc[rr], a4.y, wf4[1]);
            fma4(acc[rr], a4.z, wf4[2]); fma4(acc[rr], a4.w, wf4[3]);
            fma4(acc[rr], b4.x, wl4[0]); fma4(acc[rr], b4.y, wl4[1]);
            fma4(acc[rr], b4.z, wl4[2]); fma4(acc[rr], b4.w, wl4[3]);
        }
    }

    #pragma unroll
    for (int rr = 0; rr < 2; ++rr) {
        long row = row0 + rl * 2 + rr;
        float4 s;
        s.x = 1.0f / (1.0f + __expf(-acc[rr].x));
        s.y = 1.0f / (1.0f + __expf(-acc[rr].y));
        s.z = 1.0f / (1.0f + __expf(-acc[rr].z));
        s.w = 1.0f / (1.0f + __expf(-acc[rr].w));
        *(float4*)(qsig + row * D + dq * 4) = s;
    }
}

// ---------------------------------------------------------------------------
// K3: partial num/den over an n-chunk.
// block 320 threads = 32 d-quads (dq) x 10 p-lanes (pl); PT=50 p's/block
// (2 p-tiles total -> ek/ekv read only 2x). Each thread owns complete sums
// for its 5 contiguous p's x 4 d's. eb stride padded to 51 (bank spread).
// pnum/pden layout: [c][b][p][d].
// ---------------------------------------------------------------------------
#define PT 50
#define EBS 51
__global__ __launch_bounds__(320, 4) void aft_part_kernel(
        const float* __restrict__ cur_dist,
        const float* __restrict__ ninf,
        const float* __restrict__ ek,
        const float* __restrict__ ekv,
        const float* __restrict__ log_scale,
        const float* __restrict__ aft_alpha,
        float* __restrict__ pnum,
        float* __restrict__ pden,
        int NC, int L) {
    __shared__ float eb[128 * EBS];
    const int t = threadIdx.x;          // 0..319
    const int dq = t & 31;              // d = dq*4 .. dq*4+3
    const int pl = t >> 5;              // 0..9 -> p = p0 + pl*5 + r
    const int c  = blockIdx.x % NC;
    const int pt = (blockIdx.x / NC) % (P / PT);   // 0..1
    const int b  = blockIdx.x / (NC * (P / PT));
    const int p0 = pt * PT;
    const int n_begin = c * L;
    const int n_end = min(N, n_begin + L);
    const float lsA = log_scale[0] * aft_alpha[0];

    float4 num[5], den[5];
    #pragma unroll
    for (int i = 0; i < 5; ++i) {
        num[i] = make_float4(0.f, 0.f, 0.f, 0.f);
        den[i] = make_float4(0.f, 0.f, 0.f, 0.f);
    }

    for (int n0 = n_begin; n0 < n_end; n0 += 128) {
        const int lim = min(128, n_end - n0);
        __syncthreads();
        // stage ebias tile [lim n's][PT p's] into LDS (coalesced along n)
        for (int s = t; s < PT * 128; s += 320) {
            int nl = s & 127;
            int pp = s >> 7;
            if (nl < lim) {
                long idx = ((long)b * P + p0 + pp) * N + (n0 + nl);
                eb[nl * EBS + pp] = __expf(fmaf(-lsA, cur_dist[idx], ninf[idx]));
            }
        }
        __syncthreads();
        #pragma unroll 4
        for (int j = 0; j < lim; ++j) {
            long base = ((long)b * N + n0 + j) * D + dq * 4;
            float4 ekq = *(const float4*)(ek + base);
            float4 evq = *(const float4*)(ekv + base);
            const float* ebp = &eb[j * EBS + pl * 5];
            #pragma unroll
            for (int r = 0; r < 5; ++r) {
                float e = ebp[r];
                fma4(num[r], e, evq);
                fma4(den[r], e, ekq);
            }
        }
    }

    #pragma unroll
    for (int r = 0; r < 5; ++r) {
        int p = p0 + pl * 5 + r;
        long o = (((long)c * B + b) * P + p) * D + dq * 4;
        *(float4*)(pnum + o) = num[r];
        *(float4*)(pden + o) = den[r];
    }
}

// ---------------------------------------------------------------------------
// K4: fused partial-reduce + aft + score + clip-tanh + softmax.
// block = (b, p-tile of 10); 512 threads, thread owns n = 2t, 2t+1.
// Staging: sa[i][d] = qsig * (sum_c pnum) / (sum_c pden).
// ---------------------------------------------------------------------------
#define PT2 10
__global__ __launch_bounds__(512) void score_kernel(
        const float* __restrict__ pnum,
        const float* __restrict__ pden,
        const float* __restrict__ qsig,
        const float* __restrict__ nodesT,
        const float* __restrict__ cur_dist,
        const float* __restrict__ ninf,
        const float* __restrict__ log_scale,
        const float* __restrict__ dist_alpha,
        float* __restrict__ out, int NC) {
    __shared__ float sa[PT2][D];
    __shared__ float red[8][PT2];
    __shared__ float bmax[PT2];
    __shared__ float bsum[PT2];
    const int t = threadIdx.x;
    const int wid = t >> 6;
    const int pt = blockIdx.x % (P / PT2);
    const int b  = blockIdx.x / (P / PT2);
    const int p0 = pt * PT2;
    const float lsA = log_scale[0] * dist_alpha[0];
    const long BPD = (long)B * P * D;

    // staging: reduce NC partials -> aft rows in LDS
    for (int idx = t; idx < PT2 * D; idx += 512) {
        int i = idx >> 7;
        int d = idx & 127;
        long o = ((long)b * P + p0 + i) * D + d;
        float nsum = 0.f, dsum = 0.f;
        for (int c = 0; c < NC; ++c) {
            nsum += pnum[(long)c * BPD + o];
            dsum += pden[(long)c * BPD + o];
        }
        sa[i][d] = qsig[o] * nsum / dsum;
    }
    __syncthreads();

    const int n0 = t * 2;
    const bool act = (n0 < N);
    const int ncl = act ? n0 : 0;
    const float* ntb = nodesT + (long)b * D * N;

    float2 acc[PT2];
    #pragma unroll
    for (int i = 0; i < PT2; ++i) acc[i] = make_float2(0.f, 0.f);

    #pragma unroll 4
    for (int e0 = 0; e0 < D; e0 += 4) {
        float2 x[4];
        #pragma unroll
        for (int ee = 0; ee < 4; ++ee)
            x[ee] = *(const float2*)(ntb + (long)(e0 + ee) * N + ncl);
        #pragma unroll
        for (int i = 0; i < PT2; ++i) {
            float4 a4 = *(const float4*)(&sa[i][e0]);
            acc[i].x = fmaf(x[0].x, a4.x, acc[i].x);
            acc[i].x = fmaf(x[1].x, a4.y, acc[i].x);
            acc[i].x = fmaf(x[2].x, a4.z, acc[i].x);
            acc[i].x = fmaf(x[3].x, a4.w, acc[i].x);
            acc[i].y = fmaf(x[0].y, a4.x, acc[i].y);
            acc[i].y = fmaf(x[1].y, a4.y, acc[i].y);
            acc[i].y = fmaf(x[2].y, a4.z, acc[i].y);
            acc[i].y = fmaf(x[3].y, a4.w, acc[i].y);
        }
    }

    float2 sc[PT2];
    #pragma unroll
    for (int i = 0; i < PT2; ++i) {
        if (act) {
            long idx = ((long)b * P + p0 + i) * N + n0;
            float2 cd = *(const float2*)(cur_dist + idx);
            float2 nf = *(const float2*)(ninf + idx);
            float sx = fmaf(acc[i].x, SQRT_D_INV, -lsA * cd.x);
            float sy = fmaf(acc[i].y, SQRT_D_INV, -lsA * cd.y);
            float ax = fabsf(sx), ay = fabsf(sy);
            float rx = 1.f - 2.f / (__expf(2.f * ax) + 1.f);
            float ry = 1.f - 2.f / (__expf(2.f * ay) + 1.f);
            sc[i].x = CLIPV * copysignf(rx, sx) + nf.x;
            sc[i].y = CLIPV * copysignf(ry, sy) + nf.y;
        } else {
            sc[i].x = -INFINITY;
            sc[i].y = -INFINITY;
        }
    }

    #pragma unroll
    for (int i = 0; i < PT2; ++i) {
        float m = fmaxf(sc[i].x, sc[i].y);
        #pragma unroll
        for (int o = 1; o < 64; o <<= 1) m = fmaxf(m, __shfl_xor(m, o, 64));
        if ((t & 63) == 0) red[wid][i] = m;
    }
    __syncthreads();
    if (t < PT2) {
        float mm = red[0][t];
        #pragma unroll
        for (int w = 1; w < 8; ++w) mm = fmaxf(mm, red[w][t]);
        bmax[t] = mm;
    }
    __syncthreads();

    float2 ex[PT2];
    #pragma unroll
    for (int i = 0; i < PT2; ++i) {
        float m = bmax[i];
        ex[i].x = (sc[i].x > -1e30f) ? __expf(sc[i].x - m) : 0.f;
        ex[i].y = (sc[i].y > -1e30f) ? __expf(sc[i].y - m) : 0.f;
        float ssum = ex[i].x + ex[i].y;
        #pragma unroll
        for (int o = 1; o < 64; o <<= 1) ssum += __shfl_xor(ssum, o, 64);
        if ((t & 63) == 0) red[wid][i] = ssum;
    }
    __syncthreads();
    if (t < PT2) {
        float ss = red[0][t];
        #pragma unroll
        for (int w = 1; w < 8; ++w) ss += red[w][t];
        bsum[t] = ss;
    }
    __syncthreads();

    #pragma unroll
    for (int i = 0; i < PT2; ++i) {
        if (act) {
            float inv = 1.0f / bsum[i];
            long idx = ((long)b * P + p0 + i) * N + n0;
            *(float2*)(out + idx) = make_float2(ex[i].x * inv, ex[i].y * inv);
        }
    }
}

// ---------------------------------------------------------------------------
extern "C" void kernel_launch(void* const* d_in, const int* in_sizes, int n_in,
                              void* d_out, int out_size, void* d_ws, size_t ws_size,
                              hipStream_t stream) {
    const float* nodes      = (const float*)d_in[0];
    const float* q1         = (const float*)d_in[1];
    const float* qlast      = (const float*)d_in[2];
    const float* cur_dist   = (const float*)d_in[3];
    const float* ninf       = (const float*)d_in[4];
    const float* log_scale  = (const float*)d_in[5];
    const float* Wqf        = (const float*)d_in[6];
    const float* Wql        = (const float*)d_in[7];
    const float* Wk         = (const float*)d_in[8];
    const float* Wv         = (const float*)d_in[9];
    const float* dist_alpha = (const float*)d_in[10];
    const float* aft_alpha  = (const float*)d_in[11];
    float* out = (float*)d_out;

    const long BND = (long)B * N * D;
    const long BPD = (long)B * P * D;
    const long W2  = (long)D * D;

    float* ws     = (float*)d_ws;
    float* ek     = ws;
    float* ekv    = ek + BND;
    float* qsig   = ekv + BND;
    float* wkT    = qsig + BPD;
    float* wvT    = wkT + W2;
    float* wqfT   = wvT + W2;
    float* wqlT   = wqfT + W2;
    float* nodesT = wqlT + W2;
    float* pnum   = nodesT + BND;

    long avail = (long)(ws_size / 4) - (3 * BND + BPD + 4 * W2);
    int NC = (int)(avail / (2 * BPD));
    if (NC < 1) NC = 1;
    if (NC > 12) NC = 12;
    int L = (N + NC - 1) / NC;
    float* pden = pnum + (long)NC * BPD;

    transpose_w4<<<D, D, 0, stream>>>(Wk, Wv, Wqf, Wql, wkT, wvT, wqfT, wqlT);
    transpose_nodes<<<B * ((N + TT - 1) / TT), 256, 0, stream>>>(nodes, nodesT);
    kv_kernel<<<(B * N) / R1, 256, 0, stream>>>(nodes, wkT, wvT, ek, ekv);
    q_kernel<<<(B * P) / R2, 256, 0, stream>>>(q1, qlast, wqfT, wqlT, qsig);
    aft_part_kernel<<<B * (P / PT) * NC, 320, 0, stream>>>(
        cur_dist, ninf, ek, ekv, log_scale, aft_alpha, pnum, pden, NC, L);
    score_kernel<<<B * (P / PT2), 512, 0, stream>>>(
        pnum, pden, qsig, nodesT, cur_dist, ninf, log_scale, dist_alpha, out, NC);
}

// Round 8
// 258.841 us; speedup vs baseline: 1.1049x; 1.1049x over previous
//
#include <hip/hip_runtime.h>
#include <hip/hip_bf16.h>
#include <math.h>

#define B 32
#define P 100
#define N 1000
#define D 128

constexpr float SQRT_D_INV = 1.0f / 11.313708498984761f;
constexpr float CLIPV = 10.0f;

__device__ __forceinline__ void fma4(float4& a, float s, const float4& b) {
    a.x = fmaf(s, b.x, a.x);
    a.y = fmaf(s, b.y, a.y);
    a.z = fmaf(s, b.z, a.z);
    a.w = fmaf(s, b.w, a.w);
}

// ---------------------------------------------------------------------------
// K0: transpose all 4 weight matrices (128x128) for coalesced streaming.
// ---------------------------------------------------------------------------
__global__ void transpose_w4(const float* __restrict__ Wk,
                             const float* __restrict__ Wv,
                             const float* __restrict__ Wqf,
                             const float* __restrict__ Wql,
                             float* __restrict__ wkT,
                             float* __restrict__ wvT,
                             float* __restrict__ wqfT,
                             float* __restrict__ wqlT) {
    const int e = blockIdx.x;
    const int d = threadIdx.x;
    wkT[e * D + d]  = Wk[d * D + e];
    wvT[e * D + d]  = Wv[d * D + e];
    wqfT[e * D + d] = Wqf[d * D + e];
    wqlT[e * D + d] = Wql[d * D + e];
}

// ---------------------------------------------------------------------------
// K0b: transpose nodes -> nodesT[b][e][n].
// ---------------------------------------------------------------------------
#define TT 64
__global__ __launch_bounds__(256) void transpose_nodes(
        const float* __restrict__ nodes, float* __restrict__ nodesT) {
    __shared__ float sh[TT][D + 1];
    const int ntiles = (N + TT - 1) / TT;
    const int b  = blockIdx.x / ntiles;
    const int n0 = (blockIdx.x % ntiles) * TT;
    const int t = threadIdx.x;
    const int rows = min(TT, N - n0);

    const float4* src = (const float4*)(nodes + ((long)b * N + n0) * D);
    for (int i = t; i < rows * (D / 4); i += 256) {
        int r = i >> 5, c = i & 31;
        float4 v = src[(long)r * (D / 4) + c];
        sh[r][c * 4 + 0] = v.x; sh[r][c * 4 + 1] = v.y;
        sh[r][c * 4 + 2] = v.z; sh[r][c * 4 + 3] = v.w;
    }
    __syncthreads();

    const int nl = t & 63;
    const int eg = t >> 6;
    if (nl < rows) {
        #pragma unroll
        for (int k = 0; k < 32; ++k) {
            int e = eg * 32 + k;
            nodesT[((long)b * D + e) * N + n0 + nl] = sh[nl][e];
        }
    }
}

// ---------------------------------------------------------------------------
// K1: ek = exp(nodes @ WkT), ekv = ek * (nodes @ WvT)
// Register double-buffer on the weight stream: load e0+4 while FMA-ing e0.
// ---------------------------------------------------------------------------
#define R1 32
__global__ __launch_bounds__(256) void kv_kernel(
        const float* __restrict__ nodes,
        const float* __restrict__ wkT,
        const float* __restrict__ wvT,
        float* __restrict__ ek,
        float* __restrict__ ekv) {
    __shared__ float sh[R1][D];
    const int t = threadIdx.x;
    const int dq = t & 31;
    const int rl = t >> 5;
    const long row0 = (long)blockIdx.x * R1;

    const float4* src = (const float4*)(nodes + row0 * D);
    float4* dst = (float4*)(&sh[0][0]);
    #pragma unroll
    for (int i = 0; i < (R1 * D / 4) / 256; ++i)
        dst[t + i * 256] = src[t + i * 256];
    __syncthreads();

    float4 ka[4], va[4];
    #pragma unroll
    for (int rr = 0; rr < 4; ++rr) {
        ka[rr] = make_float4(0.f, 0.f, 0.f, 0.f);
        va[rr] = make_float4(0.f, 0.f, 0.f, 0.f);
    }

    const float* wkp = wkT + dq * 4;
    const float* wvp = wvT + dq * 4;

    float4 cwk[4], cwv[4];
    #pragma unroll
    for (int ee = 0; ee < 4; ++ee) {
        cwk[ee] = *(const float4*)(wkp + ee * D);
        cwv[ee] = *(const float4*)(wvp + ee * D);
    }

    for (int e0 = 0; e0 < D; e0 += 4) {
        float4 nwk[4], nwv[4];
        if (e0 + 4 < D) {
            #pragma unroll
            for (int ee = 0; ee < 4; ++ee) {
                nwk[ee] = *(const float4*)(wkp + (e0 + 4 + ee) * D);
                nwv[ee] = *(const float4*)(wvp + (e0 + 4 + ee) * D);
            }
        }
        #pragma unroll
        for (int rr = 0; rr < 4; ++rr) {
            float4 s4 = *(const float4*)(&sh[rl * 4 + rr][e0]);
            fma4(ka[rr], s4.x, cwk[0]); fma4(ka[rr], s4.y, cwk[1]);
            fma4(ka[rr], s4.z, cwk[2]); fma4(ka[rr], s4.w, cwk[3]);
            fma4(va[rr], s4.x, cwv[0]); fma4(va[rr], s4.y, cwv[1]);
            fma4(va[rr], s4.z, cwv[2]); fma4(va[rr], s4.w, cwv[3]);
        }
        #pragma unroll
        for (int ee = 0; ee < 4; ++ee) { cwk[ee] = nwk[ee]; cwv[ee] = nwv[ee]; }
    }

    #pragma unroll
    for (int rr = 0; rr < 4; ++rr) {
        long row = row0 + rl * 4 + rr;
        float4 e4;
        e4.x = __expf(ka[rr].x); e4.y = __expf(ka[rr].y);
        e4.z = __expf(ka[rr].z); e4.w = __expf(ka[rr].w);
        float4 ev;
        ev.x = e4.x * va[rr].x; ev.y = e4.y * va[rr].y;
        ev.z = e4.z * va[rr].z; ev.w = e4.w * va[rr].w;
        *(float4*)(ek + row * D + dq * 4) = e4;
        *(float4*)(ekv + row * D + dq * 4) = ev;
    }
}

// ---------------------------------------------------------------------------
// K2: qsig = sigmoid(q1 @ Wqf^T + qlast @ Wql^T)
// ---------------------------------------------------------------------------
#define R2 16
__global__ __launch_bounds__(256) void q_kernel(
        const float* __restrict__ q1,
        const float* __restrict__ qlast,
        const float* __restrict__ wqfT,
        const float* __restrict__ wqlT,
        float* __restrict__ qsig) {
    __shared__ float sh1[R2][D];
    __shared__ float sh2[R2][D];
    const int t = threadIdx.x;
    const int dq = t & 31;
    const int rl = t >> 5;
    const long row0 = (long)blockIdx.x * R2;

    const float4* s1 = (const float4*)(q1 + row0 * D);
    const float4* s2 = (const float4*)(qlast + row0 * D);
    float4* d1 = (float4*)(&sh1[0][0]);
    float4* d2 = (float4*)(&sh2[0][0]);
    #pragma unroll
    for (int i = 0; i < (R2 * D / 4) / 256; ++i) {
        d1[t + i * 256] = s1[t + i * 256];
        d2[t + i * 256] = s2[t + i * 256];
    }
    __syncthreads();

    float4 acc[2];
    acc[0] = make_float4(0.f, 0.f, 0.f, 0.f);
    acc[1] = make_float4(0.f, 0.f, 0.f, 0.f);

    const float* wfp = wqfT + dq * 4;
    const float* wlp = wqlT + dq * 4;

    float4 cwf[4], cwl[4];
    #pragma unroll
    for (int ee = 0; ee < 4; ++ee) {
        cwf[ee] = *(const float4*)(wfp + ee * D);
        cwl[ee] = *(const float4*)(wlp + ee * D);
    }

    for (int e0 = 0; e0 < D; e0 += 4) {
        float4 nwf[4], nwl[4];
        if (e0 + 4 < D) {
            #pragma unroll
            for (int ee = 0; ee < 4; ++ee) {
                nwf[ee] = *(const float4*)(wfp + (e0 + 4 + ee) * D);
                nwl[ee] = *(const float4*)(wlp + (e0 + 4 + ee) * D);
            }
        }
        #pragma unroll
        for (int rr = 0; rr < 2; ++rr) {
            float4 a4 = *(const float4*)(&sh1[rl * 2 + rr][e0]);
            float4 b4 = *(const float4*)(&sh2[rl * 2 + rr][e0]);
            fma4(acc[rr], a4.x, cwf[0]); fma4(acc[rr], a4.y, cwf[1]);
            fma4(acc[rr], a4.z, cwf[2]); fma4(acc[rr], a4.w, cwf[3]);
            fma4(acc[rr], b4.x, cwl[0]); fma4(acc[rr], b4.y, cwl[1]);
            fma4(acc[rr], b4.z, cwl[2]); fma4(acc[rr], b4.w, cwl[3]);
        }
        #pragma unroll
        for (int ee = 0; ee < 4; ++ee) { cwf[ee] = nwf[ee]; cwl[ee] = nwl[ee]; }
    }

    #pragma unroll
    for (int rr = 0; rr < 2; ++rr) {
        long row = row0 + rl * 2 + rr;
        float4 s;
        s.x = 1.0f / (1.0f + __expf(-acc[rr].x));
        s.y = 1.0f / (1.0f + __expf(-acc[rr].y));
        s.z = 1.0f / (1.0f + __expf(-acc[rr].z));
        s.w = 1.0f / (1.0f + __expf(-acc[rr].w));
        *(float4*)(qsig + row * D + dq * 4) = s;
    }
}

// ---------------------------------------------------------------------------
// K3: partial num/den over an n-chunk. R6-proven shape (PT=20, 128 thr,
// 2560 blocks) + register double-buffer: load j-block jb+4's ek/ekv
// (8 float4) while FMA-ing jb's 160 FMAs. Chunk lengths are multiples of 4.
// ---------------------------------------------------------------------------
#define PT 20
__global__ __launch_bounds__(128) void aft_part_kernel(
        const float* __restrict__ cur_dist,
        const float* __restrict__ ninf,
        const float* __restrict__ ek,
        const float* __restrict__ ekv,
        const float* __restrict__ log_scale,
        const float* __restrict__ aft_alpha,
        float* __restrict__ pnum,
        float* __restrict__ pden,
        int NC, int L) {
    __shared__ float eb[128][PT];
    const int t = threadIdx.x;
    const int dq = t & 31;
    const int pl = t >> 5;          // 0..3
    const int c  = blockIdx.x % NC;
    const int pt = (blockIdx.x / NC) % (P / PT);
    const int b  = blockIdx.x / (NC * (P / PT));
    const int p0 = pt * PT;
    const int n_begin = c * L;
    const int n_end = min(N, n_begin + L);
    const float lsA = log_scale[0] * aft_alpha[0];

    float4 num[5], den[5];
    #pragma unroll
    for (int i = 0; i < 5; ++i) {
        num[i] = make_float4(0.f, 0.f, 0.f, 0.f);
        den[i] = make_float4(0.f, 0.f, 0.f, 0.f);
    }

    for (int n0 = n_begin; n0 < n_end; n0 += 128) {
        const int lim = min(128, n_end - n0);   // multiple of 4
        __syncthreads();
        if (t < lim) {
            int n = n0 + t;
            #pragma unroll
            for (int i = 0; i < PT; ++i) {
                long idx = ((long)b * P + p0 + i) * N + n;
                eb[t][i] = __expf(fmaf(-lsA, cur_dist[idx], ninf[idx]));
            }
        }
        __syncthreads();

        const float* ekb = ek  + ((long)b * N + n0) * D + dq * 4;
        const float* evb = ekv + ((long)b * N + n0) * D + dq * 4;

        float4 cek[4], cev[4];
        #pragma unroll
        for (int jj = 0; jj < 4; ++jj) {
            cek[jj] = *(const float4*)(ekb + (long)jj * D);
            cev[jj] = *(const float4*)(evb + (long)jj * D);
        }

        for (int jb = 0; jb < lim; jb += 4) {
            float4 nek[4], nev[4];
            if (jb + 4 < lim) {
                #pragma unroll
                for (int jj = 0; jj < 4; ++jj) {
                    nek[jj] = *(const float4*)(ekb + (long)(jb + 4 + jj) * D);
                    nev[jj] = *(const float4*)(evb + (long)(jb + 4 + jj) * D);
                }
            }
            #pragma unroll
            for (int jj = 0; jj < 4; ++jj) {
                const int j = jb + jj;
                float4 e4 = *(const float4*)(&eb[j][pl * 4]);
                float es = eb[j][16 + pl];
                fma4(num[0], e4.x, cev[jj]); fma4(den[0], e4.x, cek[jj]);
                fma4(num[1], e4.y, cev[jj]); fma4(den[1], e4.y, cek[jj]);
                fma4(num[2], e4.z, cev[jj]); fma4(den[2], e4.z, cek[jj]);
                fma4(num[3], e4.w, cev[jj]); fma4(den[3], e4.w, cek[jj]);
                fma4(num[4], es,   cev[jj]); fma4(den[4], es,   cek[jj]);
            }
            #pragma unroll
            for (int jj = 0; jj < 4; ++jj) { cek[jj] = nek[jj]; cev[jj] = nev[jj]; }
        }
    }

    #pragma unroll
    for (int r = 0; r < 4; ++r) {
        int p = pl * 4 + r;
        long o = (((long)c * B + b) * P + p0 + p) * D + dq * 4;
        *(float4*)(pnum + o) = num[r];
        *(float4*)(pden + o) = den[r];
    }
    {
        int p = 16 + pl;
        long o = (((long)c * B + b) * P + p0 + p) * D + dq * 4;
        *(float4*)(pnum + o) = num[4];
        *(float4*)(pden + o) = den[4];
    }
}

// ---------------------------------------------------------------------------
// K4: fused partial-reduce + aft + score + clip-tanh + softmax.
// 512 threads, thread owns n = 2t, 2t+1. nodesT stream double-buffered.
// ---------------------------------------------------------------------------
#define PT2 10
__global__ __launch_bounds__(512) void score_kernel(
        const float* __restrict__ pnum,
        const float* __restrict__ pden,
        const float* __restrict__ qsig,
        const float* __restrict__ nodesT,
        const float* __restrict__ cur_dist,
        const float* __restrict__ ninf,
        const float* __restrict__ log_scale,
        const float* __restrict__ dist_alpha,
        float* __restrict__ out, int NC) {
    __shared__ float sa[PT2][D];
    __shared__ float red[8][PT2];
    __shared__ float bmax[PT2];
    __shared__ float bsum[PT2];
    const int t = threadIdx.x;
    const int wid = t >> 6;
    const int pt = blockIdx.x % (P / PT2);
    const int b  = blockIdx.x / (P / PT2);
    const int p0 = pt * PT2;
    const float lsA = log_scale[0] * dist_alpha[0];
    const long BPD = (long)B * P * D;

    // reduce NC partials -> aft rows in LDS
    for (int idx = t; idx < PT2 * D; idx += 512) {
        int i = idx >> 7;
        int d = idx & 127;
        long o = ((long)b * P + p0 + i) * D + d;
        float nsum = 0.f, dsum = 0.f;
        for (int c = 0; c < NC; ++c) {
            nsum += pnum[(long)c * BPD + o];
            dsum += pden[(long)c * BPD + o];
        }
        sa[i][d] = qsig[o] * nsum / dsum;
    }
    __syncthreads();

    const int n0 = t * 2;
    const bool act = (n0 < N);
    const int ncl = act ? n0 : 0;
    const float* ntb = nodesT + (long)b * D * N;

    float2 acc[PT2];
    #pragma unroll
    for (int i = 0; i < PT2; ++i) acc[i] = make_float2(0.f, 0.f);

    float2 cx[4];
    #pragma unroll
    for (int ee = 0; ee < 4; ++ee)
        cx[ee] = *(const float2*)(ntb + (long)ee * N + ncl);

    for (int e0 = 0; e0 < D; e0 += 4) {
        float2 nx[4];
        if (e0 + 4 < D) {
            #pragma unroll
            for (int ee = 0; ee < 4; ++ee)
                nx[ee] = *(const float2*)(ntb + (long)(e0 + 4 + ee) * N + ncl);
        }
        #pragma unroll
        for (int i = 0; i < PT2; ++i) {
            float4 a4 = *(const float4*)(&sa[i][e0]);
            acc[i].x = fmaf(cx[0].x, a4.x, acc[i].x);
            acc[i].x = fmaf(cx[1].x, a4.y, acc[i].x);
            acc[i].x = fmaf(cx[2].x, a4.z, acc[i].x);
            acc[i].x = fmaf(cx[3].x, a4.w, acc[i].x);
            acc[i].y = fmaf(cx[0].y, a4.x, acc[i].y);
            acc[i].y = fmaf(cx[1].y, a4.y, acc[i].y);
            acc[i].y = fmaf(cx[2].y, a4.z, acc[i].y);
            acc[i].y = fmaf(cx[3].y, a4.w, acc[i].y);
        }
        #pragma unroll
        for (int ee = 0; ee < 4; ++ee) cx[ee] = nx[ee];
    }

    float2 sc[PT2];
    #pragma unroll
    for (int i = 0; i < PT2; ++i) {
        if (act) {
            long idx = ((long)b * P + p0 + i) * N + n0;
            float2 cd = *(const float2*)(cur_dist + idx);
            float2 nf = *(const float2*)(ninf + idx);
            float sx = fmaf(acc[i].x, SQRT_D_INV, -lsA * cd.x);
            float sy = fmaf(acc[i].y, SQRT_D_INV, -lsA * cd.y);
            float ax = fabsf(sx), ay = fabsf(sy);
            float rx = 1.f - 2.f / (__expf(2.f * ax) + 1.f);
            float ry = 1.f - 2.f / (__expf(2.f * ay) + 1.f);
            sc[i].x = CLIPV * copysignf(rx, sx) + nf.x;
            sc[i].y = CLIPV * copysignf(ry, sy) + nf.y;
        } else {
            sc[i].x = -INFINITY;
            sc[i].y = -INFINITY;
        }
    }

    #pragma unroll
    for (int i = 0; i < PT2; ++i) {
        float m = fmaxf(sc[i].x, sc[i].y);
        #pragma unroll
        for (int o = 1; o < 64; o <<= 1) m = fmaxf(m, __shfl_xor(m, o, 64));
        if ((t & 63) == 0) red[wid][i] = m;
    }
    __syncthreads();
    if (t < PT2) {
        float mm = red[0][t];
        #pragma unroll
        for (int w = 1; w < 8; ++w) mm = fmaxf(mm, red[w][t]);
        bmax[t] = mm;
    }
    __syncthreads();

    float2 ex[PT2];
    #pragma unroll
    for (int i = 0; i < PT2; ++i) {
        float m = bmax[i];
        ex[i].x = (sc[i].x > -1e30f) ? __expf(sc[i].x - m) : 0.f;
        ex[i].y = (sc[i].y > -1e30f) ? __expf(sc[i].y - m) : 0.f;
        float ssum = ex[i].x + ex[i].y;
        #pragma unroll
        for (int o = 1; o < 64; o <<= 1) ssum += __shfl_xor(ssum, o, 64);
        if ((t & 63) == 0) red[wid][i] = ssum;
    }
    __syncthreads();
    if (t < PT2) {
        float ss = red[0][t];
        #pragma unroll
        for (int w = 1; w < 8; ++w) ss += red[w][t];
        bsum[t] = ss;
    }
    __syncthreads();

    #pragma unroll
    for (int i = 0; i < PT2; ++i) {
        if (act) {
            float inv = 1.0f / bsum[i];
            long idx = ((long)b * P + p0 + i) * N + n0;
            *(float2*)(out + idx) = make_float2(ex[i].x * inv, ex[i].y * inv);
        }
    }
}

// ---------------------------------------------------------------------------
extern "C" void kernel_launch(void* const* d_in, const int* in_sizes, int n_in,
                              void* d_out, int out_size, void* d_ws, size_t ws_size,
                              hipStream_t stream) {
    const float* nodes      = (const float*)d_in[0];
    const float* q1         = (const float*)d_in[1];
    const float* qlast      = (const float*)d_in[2];
    const float* cur_dist   = (const float*)d_in[3];
    const float* ninf       = (const float*)d_in[4];
    const float* log_scale  = (const float*)d_in[5];
    const float* Wqf        = (const float*)d_in[6];
    const float* Wql        = (const float*)d_in[7];
    const float* Wk         = (const float*)d_in[8];
    const float* Wv         = (const float*)d_in[9];
    const float* dist_alpha = (const float*)d_in[10];
    const float* aft_alpha  = (const float*)d_in[11];
    float* out = (float*)d_out;

    const long BND = (long)B * N * D;
    const long BPD = (long)B * P * D;
    const long W2  = (long)D * D;

    float* ws     = (float*)d_ws;
    float* ek     = ws;
    float* ekv    = ek + BND;
    float* qsig   = ekv + BND;
    float* wkT    = qsig + BPD;
    float* wvT    = wkT + W2;
    float* wqfT   = wvT + W2;
    float* wqlT   = wqfT + W2;
    float* nodesT = wqlT + W2;
    float* pnum   = nodesT + BND;

    long avail = (long)(ws_size / 4) - (3 * BND + BPD + 4 * W2);
    int NC = (int)(avail / (2 * BPD));
    if (NC < 1) NC = 1;
    if (NC > 16) NC = 16;
    // chunk length: multiple of 4 (pipelined j-loop has no tail; N%4==0)
    int L = (((N + NC - 1) / NC) + 3) & ~3;
    NC = (N + L - 1) / L;          // drop empty chunks
    float* pden = pnum + (long)NC * BPD;

    transpose_w4<<<D, D, 0, stream>>>(Wk, Wv, Wqf, Wql, wkT, wvT, wqfT, wqlT);
    transpose_nodes<<<B * ((N + TT - 1) / TT), 256, 0, stream>>>(nodes, nodesT);
    kv_kernel<<<(B * N) / R1, 256, 0, stream>>>(nodes, wkT, wvT, ek, ekv);
    q_kernel<<<(B * P) / R2, 256, 0, stream>>>(q1, qlast, wqfT, wqlT, qsig);
    aft_part_kernel<<<B * (P / PT) * NC, 128, 0, stream>>>(
        cur_dist, ninf, ek, ekv, log_scale, aft_alpha, pnum, pden, NC, L);
    score_kernel<<<B * (P / PT2), 512, 0, stream>>>(
        pnum, pden, qsig, nodesT, cur_dist, ninf, log_scale, dist_alpha, out, NC);
}

// Round 9
// 250.209 us; speedup vs baseline: 1.1430x; 1.0345x over previous
//
#include <hip/hip_runtime.h>
#include <hip/hip_bf16.h>
#include <math.h>

#define B 32
#define P 100
#define N 1000
#define D 128

constexpr float SQRT_D_INV = 1.0f / 11.313708498984761f;
constexpr float CLIPV = 10.0f;

__device__ __forceinline__ void fma4(float4& a, float s, const float4& b) {
    a.x = fmaf(s, b.x, a.x);
    a.y = fmaf(s, b.y, a.y);
    a.z = fmaf(s, b.z, a.z);
    a.w = fmaf(s, b.w, a.w);
}

// ---------------------------------------------------------------------------
// K0: prep = weight transposes (blocks 0..127) + nodes transpose (rest).
// ---------------------------------------------------------------------------
#define TT 64
__global__ __launch_bounds__(256) void prep_kernel(
        const float* __restrict__ nodes,
        const float* __restrict__ Wk,  const float* __restrict__ Wv,
        const float* __restrict__ Wqf, const float* __restrict__ Wql,
        float* __restrict__ wkT,  float* __restrict__ wvT,
        float* __restrict__ wqfT, float* __restrict__ wqlT,
        float* __restrict__ nodesT) {
    const int t = threadIdx.x;
    if (blockIdx.x < D) {
        const int e = blockIdx.x;
        const int d = t & 127;
        if ((t >> 7) == 0) {
            wkT[e * D + d] = Wk[d * D + e];
            wvT[e * D + d] = Wv[d * D + e];
        } else {
            wqfT[e * D + d] = Wqf[d * D + e];
            wqlT[e * D + d] = Wql[d * D + e];
        }
        return;
    }
    __shared__ float sh[TT][D + 1];
    const int blk = blockIdx.x - D;
    const int ntiles = (N + TT - 1) / TT;   // 16
    const int b  = blk / ntiles;
    const int n0 = (blk % ntiles) * TT;
    const int rows = min(TT, N - n0);

    const float4* src = (const float4*)(nodes + ((long)b * N + n0) * D);
    for (int i = t; i < rows * (D / 4); i += 256) {
        int r = i >> 5, c = i & 31;
        float4 v = src[(long)r * (D / 4) + c];
        sh[r][c * 4 + 0] = v.x; sh[r][c * 4 + 1] = v.y;
        sh[r][c * 4 + 2] = v.z; sh[r][c * 4 + 3] = v.w;
    }
    __syncthreads();

    const int nl = t & 63;
    const int eg = t >> 6;
    if (nl < rows) {
        #pragma unroll
        for (int k = 0; k < 32; ++k) {
            int e = eg * 32 + k;
            nodesT[((long)b * D + e) * N + n0 + nl] = sh[nl][e];
        }
    }
}

// ---------------------------------------------------------------------------
// K1: ek = exp(nodes @ WkT), ekv = ek * (nodes @ WvT)  (R8-proven)
// ---------------------------------------------------------------------------
#define R1 32
__global__ __launch_bounds__(256) void kv_kernel(
        const float* __restrict__ nodes,
        const float* __restrict__ wkT,
        const float* __restrict__ wvT,
        float* __restrict__ ek,
        float* __restrict__ ekv) {
    __shared__ float sh[R1][D];
    const int t = threadIdx.x;
    const int dq = t & 31;
    const int rl = t >> 5;
    const long row0 = (long)blockIdx.x * R1;

    const float4* src = (const float4*)(nodes + row0 * D);
    float4* dst = (float4*)(&sh[0][0]);
    #pragma unroll
    for (int i = 0; i < (R1 * D / 4) / 256; ++i)
        dst[t + i * 256] = src[t + i * 256];
    __syncthreads();

    float4 ka[4], va[4];
    #pragma unroll
    for (int rr = 0; rr < 4; ++rr) {
        ka[rr] = make_float4(0.f, 0.f, 0.f, 0.f);
        va[rr] = make_float4(0.f, 0.f, 0.f, 0.f);
    }

    const float* wkp = wkT + dq * 4;
    const float* wvp = wvT + dq * 4;

    float4 cwk[4], cwv[4];
    #pragma unroll
    for (int ee = 0; ee < 4; ++ee) {
        cwk[ee] = *(const float4*)(wkp + ee * D);
        cwv[ee] = *(const float4*)(wvp + ee * D);
    }

    for (int e0 = 0; e0 < D; e0 += 4) {
        float4 nwk[4], nwv[4];
        if (e0 + 4 < D) {
            #pragma unroll
            for (int ee = 0; ee < 4; ++ee) {
                nwk[ee] = *(const float4*)(wkp + (e0 + 4 + ee) * D);
                nwv[ee] = *(const float4*)(wvp + (e0 + 4 + ee) * D);
            }
        }
        #pragma unroll
        for (int rr = 0; rr < 4; ++rr) {
            float4 s4 = *(const float4*)(&sh[rl * 4 + rr][e0]);
            fma4(ka[rr], s4.x, cwk[0]); fma4(ka[rr], s4.y, cwk[1]);
            fma4(ka[rr], s4.z, cwk[2]); fma4(ka[rr], s4.w, cwk[3]);
            fma4(va[rr], s4.x, cwv[0]); fma4(va[rr], s4.y, cwv[1]);
            fma4(va[rr], s4.z, cwv[2]); fma4(va[rr], s4.w, cwv[3]);
        }
        #pragma unroll
        for (int ee = 0; ee < 4; ++ee) { cwk[ee] = nwk[ee]; cwv[ee] = nwv[ee]; }
    }

    #pragma unroll
    for (int rr = 0; rr < 4; ++rr) {
        long row = row0 + rl * 4 + rr;
        float4 e4;
        e4.x = __expf(ka[rr].x); e4.y = __expf(ka[rr].y);
        e4.z = __expf(ka[rr].z); e4.w = __expf(ka[rr].w);
        float4 ev;
        ev.x = e4.x * va[rr].x; ev.y = e4.y * va[rr].y;
        ev.z = e4.z * va[rr].z; ev.w = e4.w * va[rr].w;
        *(float4*)(ek + row * D + dq * 4) = e4;
        *(float4*)(ekv + row * D + dq * 4) = ev;
    }
}

// ---------------------------------------------------------------------------
// K2: qsig = sigmoid(q1 @ Wqf^T + qlast @ Wql^T)  (R8-proven)
// ---------------------------------------------------------------------------
#define R2 16
__global__ __launch_bounds__(256) void q_kernel(
        const float* __restrict__ q1,
        const float* __restrict__ qlast,
        const float* __restrict__ wqfT,
        const float* __restrict__ wqlT,
        float* __restrict__ qsig) {
    __shared__ float sh1[R2][D];
    __shared__ float sh2[R2][D];
    const int t = threadIdx.x;
    const int dq = t & 31;
    const int rl = t >> 5;
    const long row0 = (long)blockIdx.x * R2;

    const float4* s1 = (const float4*)(q1 + row0 * D);
    const float4* s2 = (const float4*)(qlast + row0 * D);
    float4* d1 = (float4*)(&sh1[0][0]);
    float4* d2 = (float4*)(&sh2[0][0]);
    #pragma unroll
    for (int i = 0; i < (R2 * D / 4) / 256; ++i) {
        d1[t + i * 256] = s1[t + i * 256];
        d2[t + i * 256] = s2[t + i * 256];
    }
    __syncthreads();

    float4 acc[2];
    acc[0] = make_float4(0.f, 0.f, 0.f, 0.f);
    acc[1] = make_float4(0.f, 0.f, 0.f, 0.f);

    const float* wfp = wqfT + dq * 4;
    const float* wlp = wqlT + dq * 4;

    float4 cwf[4], cwl[4];
    #pragma unroll
    for (int ee = 0; ee < 4; ++ee) {
        cwf[ee] = *(const float4*)(wfp + ee * D);
        cwl[ee] = *(const float4*)(wlp + ee * D);
    }

    for (int e0 = 0; e0 < D; e0 += 4) {
        float4 nwf[4], nwl[4];
        if (e0 + 4 < D) {
            #pragma unroll
            for (int ee = 0; ee < 4; ++ee) {
                nwf[ee] = *(const float4*)(wfp + (e0 + 4 + ee) * D);
                nwl[ee] = *(const float4*)(wlp + (e0 + 4 + ee) * D);
            }
        }
        #pragma unroll
        for (int rr = 0; rr < 2; ++rr) {
            float4 a4 = *(const float4*)(&sh1[rl * 2 + rr][e0]);
            float4 b4 = *(const float4*)(&sh2[rl * 2 + rr][e0]);
            fma4(acc[rr], a4.x, cwf[0]); fma4(acc[rr], a4.y, cwf[1]);
            fma4(acc[rr], a4.z, cwf[2]); fma4(acc[rr], a4.w, cwf[3]);
            fma4(acc[rr], b4.x, cwl[0]); fma4(acc[rr], b4.y, cwl[1]);
            fma4(acc[rr], b4.z, cwl[2]); fma4(acc[rr], b4.w, cwl[3]);
        }
        #pragma unroll
        for (int ee = 0; ee < 4; ++ee) { cwf[ee] = nwf[ee]; cwl[ee] = nwl[ee]; }
    }

    #pragma unroll
    for (int rr = 0; rr < 2; ++rr) {
        long row = row0 + rl * 2 + rr;
        float4 s;
        s.x = 1.0f / (1.0f + __expf(-acc[rr].x));
        s.y = 1.0f / (1.0f + __expf(-acc[rr].y));
        s.z = 1.0f / (1.0f + __expf(-acc[rr].z));
        s.w = 1.0f / (1.0f + __expf(-acc[rr].w));
        *(float4*)(qsig + row * D + dq * 4) = s;
    }
}

// ---------------------------------------------------------------------------
// K3: partial num/den over an n-chunk.
// 128 thr = 32 dq x 4 pl, PT=20 (pl owns p0+pl*5..+4).
// Staging tiles of TS=32 n's: LDS ping-pong + register prefetch — global
// loads for tile k+1 issued before consuming tile k. One barrier per tile.
// eb[buf][n][p] row stride 33 -> conflict-free stores, b32 broadcast reads.
// ---------------------------------------------------------------------------
#define PT 20
#define TS 32
__global__ __launch_bounds__(128) void aft_part_kernel(
        const float* __restrict__ cur_dist,
        const float* __restrict__ ninf,
        const float* __restrict__ ek,
        const float* __restrict__ ekv,
        const float* __restrict__ log_scale,
        const float* __restrict__ aft_alpha,
        float* __restrict__ pnum,
        float* __restrict__ pden,
        int NC, int L) {
    __shared__ float eb[2][TS][33];
    const int t = threadIdx.x;
    const int dq = t & 31;
    const int pl = t >> 5;              // 0..3
    const int pl5 = pl * 5;
    const int c  = blockIdx.x % NC;
    const int pt = (blockIdx.x / NC) % (P / PT);
    const int b  = blockIdx.x / (NC * (P / PT));
    const int p0 = pt * PT;
    const int n_begin = c * L;
    const int n_end = min(N, n_begin + L);
    const float lsA = log_scale[0] * aft_alpha[0];

    float4 num[5], den[5];
    #pragma unroll
    for (int i = 0; i < 5; ++i) {
        num[i] = make_float4(0.f, 0.f, 0.f, 0.f);
        den[i] = make_float4(0.f, 0.f, 0.f, 0.f);
    }

    // this thread's 5 staging slots: s = t + k*128 -> (pp = s>>5, nl = s&31)
    float rv[5];
    int n0 = n_begin;
    int ts = min(TS, n_end - n0);

    // prime: load tile 0
    #pragma unroll
    for (int k = 0; k < 5; ++k) {
        int s = t + k * 128;
        int pp = s >> 5, nl = s & 31;
        rv[k] = 0.f;
        if (nl < ts) {
            long idx = ((long)b * P + p0 + pp) * N + (n0 + nl);
            rv[k] = fmaf(-lsA, cur_dist[idx], ninf[idx]);
        }
    }

    int buf = 0;
    while (n0 < n_end) {
        // regs -> LDS[buf] (exp applied here)
        #pragma unroll
        for (int k = 0; k < 5; ++k) {
            int s = t + k * 128;
            int pp = s >> 5, nl = s & 31;
            if (nl < ts) eb[buf][nl][pp] = __expf(rv[k]);
        }
        __syncthreads();

        // prefetch next tile into regs (latency hidden under j-loop)
        const int n0n = n0 + ts;
        const int tsn = min(TS, n_end - n0n);
        if (n0n < n_end) {
            #pragma unroll
            for (int k = 0; k < 5; ++k) {
                int s = t + k * 128;
                int pp = s >> 5, nl = s & 31;
                rv[k] = 0.f;
                if (nl < tsn) {
                    long idx = ((long)b * P + p0 + pp) * N + (n0n + nl);
                    rv[k] = fmaf(-lsA, cur_dist[idx], ninf[idx]);
                }
            }
        }

        // consume tile
        const float* ekb = ek  + ((long)b * N + n0) * D + dq * 4;
        const float* evb = ekv + ((long)b * N + n0) * D + dq * 4;
        #pragma unroll 4
        for (int j = 0; j < ts; ++j) {
            float4 ekq = *(const float4*)(ekb + (long)j * D);
            float4 evq = *(const float4*)(evb + (long)j * D);
            float e0 = eb[buf][j][pl5 + 0];
            float e1 = eb[buf][j][pl5 + 1];
            float e2 = eb[buf][j][pl5 + 2];
            float e3 = eb[buf][j][pl5 + 3];
            float e4 = eb[buf][j][pl5 + 4];
            fma4(num[0], e0, evq); fma4(den[0], e0, ekq);
            fma4(num[1], e1, evq); fma4(den[1], e1, ekq);
            fma4(num[2], e2, evq); fma4(den[2], e2, ekq);
            fma4(num[3], e3, evq); fma4(den[3], e3, ekq);
            fma4(num[4], e4, evq); fma4(den[4], e4, ekq);
        }
        buf ^= 1;
        n0 = n0n;
        ts = tsn;
    }

    #pragma unroll
    for (int r = 0; r < 5; ++r) {
        int p = p0 + pl5 + r;
        long o = (((long)c * B + b) * P + p) * D + dq * 4;
        *(float4*)(pnum + o) = num[r];
        *(float4*)(pden + o) = den[r];
    }
}

// ---------------------------------------------------------------------------
// K4: fused partial-reduce + aft + score + clip-tanh + softmax (R8-proven).
// ---------------------------------------------------------------------------
#define PT2 10
__global__ __launch_bounds__(512) void score_kernel(
        const float* __restrict__ pnum,
        const float* __restrict__ pden,
        const float* __restrict__ qsig,
        const float* __restrict__ nodesT,
        const float* __restrict__ cur_dist,
        const float* __restrict__ ninf,
        const float* __restrict__ log_scale,
        const float* __restrict__ dist_alpha,
        float* __restrict__ out, int NC) {
    __shared__ float sa[PT2][D];
    __shared__ float red[8][PT2];
    __shared__ float bmax[PT2];
    __shared__ float bsum[PT2];
    const int t = threadIdx.x;
    const int wid = t >> 6;
    const int pt = blockIdx.x % (P / PT2);
    const int b  = blockIdx.x / (P / PT2);
    const int p0 = pt * PT2;
    const float lsA = log_scale[0] * dist_alpha[0];
    const long BPD = (long)B * P * D;

    for (int idx = t; idx < PT2 * D; idx += 512) {
        int i = idx >> 7;
        int d = idx & 127;
        long o = ((long)b * P + p0 + i) * D + d;
        float nsum = 0.f, dsum = 0.f;
        for (int c = 0; c < NC; ++c) {
            nsum += pnum[(long)c * BPD + o];
            dsum += pden[(long)c * BPD + o];
        }
        sa[i][d] = qsig[o] * nsum / dsum;
    }
    __syncthreads();

    const int n0 = t * 2;
    const bool act = (n0 < N);
    const int ncl = act ? n0 : 0;
    const float* ntb = nodesT + (long)b * D * N;

    float2 acc[PT2];
    #pragma unroll
    for (int i = 0; i < PT2; ++i) acc[i] = make_float2(0.f, 0.f);

    float2 cx[4];
    #pragma unroll
    for (int ee = 0; ee < 4; ++ee)
        cx[ee] = *(const float2*)(ntb + (long)ee * N + ncl);

    for (int e0 = 0; e0 < D; e0 += 4) {
        float2 nx[4];
        if (e0 + 4 < D) {
            #pragma unroll
            for (int ee = 0; ee < 4; ++ee)
                nx[ee] = *(const float2*)(ntb + (long)(e0 + 4 + ee) * N + ncl);
        }
        #pragma unroll
        for (int i = 0; i < PT2; ++i) {
            float4 a4 = *(const float4*)(&sa[i][e0]);
            acc[i].x = fmaf(cx[0].x, a4.x, acc[i].x);
            acc[i].x = fmaf(cx[1].x, a4.y, acc[i].x);
            acc[i].x = fmaf(cx[2].x, a4.z, acc[i].x);
            acc[i].x = fmaf(cx[3].x, a4.w, acc[i].x);
            acc[i].y = fmaf(cx[0].y, a4.x, acc[i].y);
            acc[i].y = fmaf(cx[1].y, a4.y, acc[i].y);
            acc[i].y = fmaf(cx[2].y, a4.z, acc[i].y);
            acc[i].y = fmaf(cx[3].y, a4.w, acc[i].y);
        }
        #pragma unroll
        for (int ee = 0; ee < 4; ++ee) cx[ee] = nx[ee];
    }

    float2 sc[PT2];
    #pragma unroll
    for (int i = 0; i < PT2; ++i) {
        if (act) {
            long idx = ((long)b * P + p0 + i) * N + n0;
            float2 cd = *(const float2*)(cur_dist + idx);
            float2 nf = *(const float2*)(ninf + idx);
            float sx = fmaf(acc[i].x, SQRT_D_INV, -lsA * cd.x);
            float sy = fmaf(acc[i].y, SQRT_D_INV, -lsA * cd.y);
            float ax = fabsf(sx), ay = fabsf(sy);
            float rx = 1.f - 2.f / (__expf(2.f * ax) + 1.f);
            float ry = 1.f - 2.f / (__expf(2.f * ay) + 1.f);
            sc[i].x = CLIPV * copysignf(rx, sx) + nf.x;
            sc[i].y = CLIPV * copysignf(ry, sy) + nf.y;
        } else {
            sc[i].x = -INFINITY;
            sc[i].y = -INFINITY;
        }
    }

    #pragma unroll
    for (int i = 0; i < PT2; ++i) {
        float m = fmaxf(sc[i].x, sc[i].y);
        #pragma unroll
        for (int o = 1; o < 64; o <<= 1) m = fmaxf(m, __shfl_xor(m, o, 64));
        if ((t & 63) == 0) red[wid][i] = m;
    }
    __syncthreads();
    if (t < PT2) {
        float mm = red[0][t];
        #pragma unroll
        for (int w = 1; w < 8; ++w) mm = fmaxf(mm, red[w][t]);
        bmax[t] = mm;
    }
    __syncthreads();

    float2 ex[PT2];
    #pragma unroll
    for (int i = 0; i < PT2; ++i) {
        float m = bmax[i];
        ex[i].x = (sc[i].x > -1e30f) ? __expf(sc[i].x - m) : 0.f;
        ex[i].y = (sc[i].y > -1e30f) ? __expf(sc[i].y - m) : 0.f;
        float ssum = ex[i].x + ex[i].y;
        #pragma unroll
        for (int o = 1; o < 64; o <<= 1) ssum += __shfl_xor(ssum, o, 64);
        if ((t & 63) == 0) red[wid][i] = ssum;
    }
    __syncthreads();
    if (t < PT2) {
        float ss = red[0][t];
        #pragma unroll
        for (int w = 1; w < 8; ++w) ss += red[w][t];
        bsum[t] = ss;
    }
    __syncthreads();

    #pragma unroll
    for (int i = 0; i < PT2; ++i) {
        if (act) {
            float inv = 1.0f / bsum[i];
            long idx = ((long)b * P + p0 + i) * N + n0;
            *(float2*)(out + idx) = make_float2(ex[i].x * inv, ex[i].y * inv);
        }
    }
}

// ---------------------------------------------------------------------------
extern "C" void kernel_launch(void* const* d_in, const int* in_sizes, int n_in,
                              void* d_out, int out_size, void* d_ws, size_t ws_size,
                              hipStream_t stream) {
    const float* nodes      = (const float*)d_in[0];
    const float* q1         = (const float*)d_in[1];
    const float* qlast      = (const float*)d_in[2];
    const float* cur_dist   = (const float*)d_in[3];
    const float* ninf       = (const float*)d_in[4];
    const float* log_scale  = (const float*)d_in[5];
    const float* Wqf        = (const float*)d_in[6];
    const float* Wql        = (const float*)d_in[7];
    const float* Wk         = (const float*)d_in[8];
    const float* Wv         = (const float*)d_in[9];
    const float* dist_alpha = (const float*)d_in[10];
    const float* aft_alpha  = (const float*)d_in[11];
    float* out = (float*)d_out;

    const long BND = (long)B * N * D;
    const long BPD = (long)B * P * D;
    const long W2  = (long)D * D;

    float* ws     = (float*)d_ws;
    float* ek     = ws;
    float* ekv    = ek + BND;
    float* qsig   = ekv + BND;
    float* wkT    = qsig + BPD;
    float* wvT    = wkT + W2;
    float* wqfT   = wvT + W2;
    float* wqlT   = wqfT + W2;
    float* nodesT = wqlT + W2;
    float* pnum   = nodesT + BND;

    long avail = (long)(ws_size / 4) - (3 * BND + BPD + 4 * W2);
    int NC = (int)(avail / (2 * BPD));
    if (NC < 1) NC = 1;
    if (NC > 12) NC = 12;
    int L = (N + NC - 1) / NC;
    NC = (N + L - 1) / L;
    float* pden = pnum + (long)NC * BPD;

    prep_kernel<<<D + B * ((N + TT - 1) / TT), 256, 0, stream>>>(
        nodes, Wk, Wv, Wqf, Wql, wkT, wvT, wqfT, wqlT, nodesT);
    kv_kernel<<<(B * N) / R1, 256, 0, stream>>>(nodes, wkT, wvT, ek, ekv);
    q_kernel<<<(B * P) / R2, 256, 0, stream>>>(q1, qlast, wqfT, wqlT, qsig);
    aft_part_kernel<<<B * (P / PT) * NC, 128, 0, stream>>>(
        cur_dist, ninf, ek, ekv, log_scale, aft_alpha, pnum, pden, NC, L);
    score_kernel<<<B * (P / PT2), 512, 0, stream>>>(
        pnum, pden, qsig, nodesT, cur_dist, ninf, log_scale, dist_alpha, out, NC);
}

// Round 10
// 247.591 us; speedup vs baseline: 1.1551x; 1.0106x over previous
//
#include <hip/hip_runtime.h>
#include <hip/hip_bf16.h>
#include <math.h>

#define B 32
#define P 100
#define N 1000
#define D 128

constexpr float SQRT_D_INV = 1.0f / 11.313708498984761f;
constexpr float CLIPV = 10.0f;

__device__ __forceinline__ void fma4(float4& a, float s, const float4& b) {
    a.x = fmaf(s, b.x, a.x);
    a.y = fmaf(s, b.y, a.y);
    a.z = fmaf(s, b.z, a.z);
    a.w = fmaf(s, b.w, a.w);
}

// ---------------------------------------------------------------------------
// K0: prep = weight transposes (blocks 0..127) + nodes transpose (rest).
// ---------------------------------------------------------------------------
#define TT 64
__global__ __launch_bounds__(256) void prep_kernel(
        const float* __restrict__ nodes,
        const float* __restrict__ Wk,  const float* __restrict__ Wv,
        const float* __restrict__ Wqf, const float* __restrict__ Wql,
        float* __restrict__ wkT,  float* __restrict__ wvT,
        float* __restrict__ wqfT, float* __restrict__ wqlT,
        float* __restrict__ nodesT) {
    const int t = threadIdx.x;
    if (blockIdx.x < D) {
        const int e = blockIdx.x;
        const int d = t & 127;
        if ((t >> 7) == 0) {
            wkT[e * D + d] = Wk[d * D + e];
            wvT[e * D + d] = Wv[d * D + e];
        } else {
            wqfT[e * D + d] = Wqf[d * D + e];
            wqlT[e * D + d] = Wql[d * D + e];
        }
        return;
    }
    __shared__ float sh[TT][D + 1];
    const int blk = blockIdx.x - D;
    const int ntiles = (N + TT - 1) / TT;   // 16
    const int b  = blk / ntiles;
    const int n0 = (blk % ntiles) * TT;
    const int rows = min(TT, N - n0);

    const float4* src = (const float4*)(nodes + ((long)b * N + n0) * D);
    for (int i = t; i < rows * (D / 4); i += 256) {
        int r = i >> 5, c = i & 31;
        float4 v = src[(long)r * (D / 4) + c];
        sh[r][c * 4 + 0] = v.x; sh[r][c * 4 + 1] = v.y;
        sh[r][c * 4 + 2] = v.z; sh[r][c * 4 + 3] = v.w;
    }
    __syncthreads();

    const int nl = t & 63;
    const int eg = t >> 6;
    if (nl < rows) {
        #pragma unroll
        for (int k = 0; k < 32; ++k) {
            int e = eg * 32 + k;
            nodesT[((long)b * D + e) * N + n0 + nl] = sh[nl][e];
        }
    }
}

// ---------------------------------------------------------------------------
// K1: ek = exp(nodes @ WkT), ekv = ek * (nodes @ WvT)  (R8-proven)
// ---------------------------------------------------------------------------
#define R1 32
__global__ __launch_bounds__(256) void kv_kernel(
        const float* __restrict__ nodes,
        const float* __restrict__ wkT,
        const float* __restrict__ wvT,
        float* __restrict__ ek,
        float* __restrict__ ekv) {
    __shared__ float sh[R1][D];
    const int t = threadIdx.x;
    const int dq = t & 31;
    const int rl = t >> 5;
    const long row0 = (long)blockIdx.x * R1;

    const float4* src = (const float4*)(nodes + row0 * D);
    float4* dst = (float4*)(&sh[0][0]);
    #pragma unroll
    for (int i = 0; i < (R1 * D / 4) / 256; ++i)
        dst[t + i * 256] = src[t + i * 256];
    __syncthreads();

    float4 ka[4], va[4];
    #pragma unroll
    for (int rr = 0; rr < 4; ++rr) {
        ka[rr] = make_float4(0.f, 0.f, 0.f, 0.f);
        va[rr] = make_float4(0.f, 0.f, 0.f, 0.f);
    }

    const float* wkp = wkT + dq * 4;
    const float* wvp = wvT + dq * 4;

    float4 cwk[4], cwv[4];
    #pragma unroll
    for (int ee = 0; ee < 4; ++ee) {
        cwk[ee] = *(const float4*)(wkp + ee * D);
        cwv[ee] = *(const float4*)(wvp + ee * D);
    }

    for (int e0 = 0; e0 < D; e0 += 4) {
        float4 nwk[4], nwv[4];
        if (e0 + 4 < D) {
            #pragma unroll
            for (int ee = 0; ee < 4; ++ee) {
                nwk[ee] = *(const float4*)(wkp + (e0 + 4 + ee) * D);
                nwv[ee] = *(const float4*)(wvp + (e0 + 4 + ee) * D);
            }
        }
        #pragma unroll
        for (int rr = 0; rr < 4; ++rr) {
            float4 s4 = *(const float4*)(&sh[rl * 4 + rr][e0]);
            fma4(ka[rr], s4.x, cwk[0]); fma4(ka[rr], s4.y, cwk[1]);
            fma4(ka[rr], s4.z, cwk[2]); fma4(ka[rr], s4.w, cwk[3]);
            fma4(va[rr], s4.x, cwv[0]); fma4(va[rr], s4.y, cwv[1]);
            fma4(va[rr], s4.z, cwv[2]); fma4(va[rr], s4.w, cwv[3]);
        }
        #pragma unroll
        for (int ee = 0; ee < 4; ++ee) { cwk[ee] = nwk[ee]; cwv[ee] = nwv[ee]; }
    }

    #pragma unroll
    for (int rr = 0; rr < 4; ++rr) {
        long row = row0 + rl * 4 + rr;
        float4 e4;
        e4.x = __expf(ka[rr].x); e4.y = __expf(ka[rr].y);
        e4.z = __expf(ka[rr].z); e4.w = __expf(ka[rr].w);
        float4 ev;
        ev.x = e4.x * va[rr].x; ev.y = e4.y * va[rr].y;
        ev.z = e4.z * va[rr].z; ev.w = e4.w * va[rr].w;
        *(float4*)(ek + row * D + dq * 4) = e4;
        *(float4*)(ekv + row * D + dq * 4) = ev;
    }
}

// ---------------------------------------------------------------------------
// K2: qsig = sigmoid(q1 @ Wqf^T + qlast @ Wql^T)  (R8-proven)
// ---------------------------------------------------------------------------
#define R2 16
__global__ __launch_bounds__(256) void q_kernel(
        const float* __restrict__ q1,
        const float* __restrict__ qlast,
        const float* __restrict__ wqfT,
        const float* __restrict__ wqlT,
        float* __restrict__ qsig) {
    __shared__ float sh1[R2][D];
    __shared__ float sh2[R2][D];
    const int t = threadIdx.x;
    const int dq = t & 31;
    const int rl = t >> 5;
    const long row0 = (long)blockIdx.x * R2;

    const float4* s1 = (const float4*)(q1 + row0 * D);
    const float4* s2 = (const float4*)(qlast + row0 * D);
    float4* d1 = (float4*)(&sh1[0][0]);
    float4* d2 = (float4*)(&sh2[0][0]);
    #pragma unroll
    for (int i = 0; i < (R2 * D / 4) / 256; ++i) {
        d1[t + i * 256] = s1[t + i * 256];
        d2[t + i * 256] = s2[t + i * 256];
    }
    __syncthreads();

    float4 acc[2];
    acc[0] = make_float4(0.f, 0.f, 0.f, 0.f);
    acc[1] = make_float4(0.f, 0.f, 0.f, 0.f);

    const float* wfp = wqfT + dq * 4;
    const float* wlp = wqlT + dq * 4;

    float4 cwf[4], cwl[4];
    #pragma unroll
    for (int ee = 0; ee < 4; ++ee) {
        cwf[ee] = *(const float4*)(wfp + ee * D);
        cwl[ee] = *(const float4*)(wlp + ee * D);
    }

    for (int e0 = 0; e0 < D; e0 += 4) {
        float4 nwf[4], nwl[4];
        if (e0 + 4 < D) {
            #pragma unroll
            for (int ee = 0; ee < 4; ++ee) {
                nwf[ee] = *(const float4*)(wfp + (e0 + 4 + ee) * D);
                nwl[ee] = *(const float4*)(wlp + (e0 + 4 + ee) * D);
            }
        }
        #pragma unroll
        for (int rr = 0; rr < 2; ++rr) {
            float4 a4 = *(const float4*)(&sh1[rl * 2 + rr][e0]);
            float4 b4 = *(const float4*)(&sh2[rl * 2 + rr][e0]);
            fma4(acc[rr], a4.x, cwf[0]); fma4(acc[rr], a4.y, cwf[1]);
            fma4(acc[rr], a4.z, cwf[2]); fma4(acc[rr], a4.w, cwf[3]);
            fma4(acc[rr], b4.x, cwl[0]); fma4(acc[rr], b4.y, cwl[1]);
            fma4(acc[rr], b4.z, cwl[2]); fma4(acc[rr], b4.w, cwl[3]);
        }
        #pragma unroll
        for (int ee = 0; ee < 4; ++ee) { cwf[ee] = nwf[ee]; cwl[ee] = nwl[ee]; }
    }

    #pragma unroll
    for (int rr = 0; rr < 2; ++rr) {
        long row = row0 + rl * 2 + rr;
        float4 s;
        s.x = 1.0f / (1.0f + __expf(-acc[rr].x));
        s.y = 1.0f / (1.0f + __expf(-acc[rr].y));
        s.z = 1.0f / (1.0f + __expf(-acc[rr].z));
        s.w = 1.0f / (1.0f + __expf(-acc[rr].w));
        *(float4*)(qsig + row * D + dq * 4) = s;
    }
}

// ---------------------------------------------------------------------------
// K3: partial num/den over an n-chunk (R9-proven ping-pong staging).
// Block index: b fastest (stride B % 8 == 0 -> same-b blocks share an XCD,
// ek/ekv slices stay L2-resident).
// ---------------------------------------------------------------------------
#define PT 20
#define TS 32
__global__ __launch_bounds__(128) void aft_part_kernel(
        const float* __restrict__ cur_dist,
        const float* __restrict__ ninf,
        const float* __restrict__ ek,
        const float* __restrict__ ekv,
        const float* __restrict__ log_scale,
        const float* __restrict__ aft_alpha,
        float* __restrict__ pnum,
        float* __restrict__ pden,
        int NC, int L) {
    __shared__ float eb[2][TS][33];
    const int t = threadIdx.x;
    const int dq = t & 31;
    const int pl = t >> 5;
    const int pl5 = pl * 5;
    const int b    = blockIdx.x % B;            // b fastest -> XCD locality
    const int rest = blockIdx.x / B;
    const int c    = rest % NC;
    const int pt   = rest / NC;
    const int p0 = pt * PT;
    const int n_begin = c * L;
    const int n_end = min(N, n_begin + L);
    const float lsA = log_scale[0] * aft_alpha[0];

    float4 num[5], den[5];
    #pragma unroll
    for (int i = 0; i < 5; ++i) {
        num[i] = make_float4(0.f, 0.f, 0.f, 0.f);
        den[i] = make_float4(0.f, 0.f, 0.f, 0.f);
    }

    float rv[5];
    int n0 = n_begin;
    int ts = min(TS, n_end - n0);

    #pragma unroll
    for (int k = 0; k < 5; ++k) {
        int s = t + k * 128;
        int pp = s >> 5, nl = s & 31;
        rv[k] = 0.f;
        if (nl < ts) {
            long idx = ((long)b * P + p0 + pp) * N + (n0 + nl);
            rv[k] = fmaf(-lsA, cur_dist[idx], ninf[idx]);
        }
    }

    int buf = 0;
    while (n0 < n_end) {
        #pragma unroll
        for (int k = 0; k < 5; ++k) {
            int s = t + k * 128;
            int pp = s >> 5, nl = s & 31;
            if (nl < ts) eb[buf][nl][pp] = __expf(rv[k]);
        }
        __syncthreads();

        const int n0n = n0 + ts;
        const int tsn = min(TS, n_end - n0n);
        if (n0n < n_end) {
            #pragma unroll
            for (int k = 0; k < 5; ++k) {
                int s = t + k * 128;
                int pp = s >> 5, nl = s & 31;
                rv[k] = 0.f;
                if (nl < tsn) {
                    long idx = ((long)b * P + p0 + pp) * N + (n0n + nl);
                    rv[k] = fmaf(-lsA, cur_dist[idx], ninf[idx]);
                }
            }
        }

        const float* ekb = ek  + ((long)b * N + n0) * D + dq * 4;
        const float* evb = ekv + ((long)b * N + n0) * D + dq * 4;
        #pragma unroll 4
        for (int j = 0; j < ts; ++j) {
            float4 ekq = *(const float4*)(ekb + (long)j * D);
            float4 evq = *(const float4*)(evb + (long)j * D);
            float e0 = eb[buf][j][pl5 + 0];
            float e1 = eb[buf][j][pl5 + 1];
            float e2 = eb[buf][j][pl5 + 2];
            float e3 = eb[buf][j][pl5 + 3];
            float e4 = eb[buf][j][pl5 + 4];
            fma4(num[0], e0, evq); fma4(den[0], e0, ekq);
            fma4(num[1], e1, evq); fma4(den[1], e1, ekq);
            fma4(num[2], e2, evq); fma4(den[2], e2, ekq);
            fma4(num[3], e3, evq); fma4(den[3], e3, ekq);
            fma4(num[4], e4, evq); fma4(den[4], e4, ekq);
        }
        buf ^= 1;
        n0 = n0n;
        ts = tsn;
    }

    #pragma unroll
    for (int r = 0; r < 5; ++r) {
        int p = p0 + pl5 + r;
        long o = (((long)c * B + b) * P + p) * D + dq * 4;
        *(float4*)(pnum + o) = num[r];
        *(float4*)(pden + o) = den[r];
    }
}

// ---------------------------------------------------------------------------
// K3b: reduce chunks -> aft = qsig * num / den  (highly parallel).
// ---------------------------------------------------------------------------
__global__ __launch_bounds__(256) void aft_reduce_kernel(
        const float* __restrict__ pnum,
        const float* __restrict__ pden,
        const float* __restrict__ qsig,
        float* __restrict__ aft,
        int NC) {
    const long i = (long)blockIdx.x * 256 + threadIdx.x;
    const long BPD = (long)B * P * D;
    float n = 0.f, d = 0.f;
    for (int c = 0; c < NC; ++c) {
        n += pnum[(long)c * BPD + i];
        d += pden[(long)c * BPD + i];
    }
    aft[i] = qsig[i] * n / d;
}

// ---------------------------------------------------------------------------
// K4a: score_part — scores are bounded (|10*tanh|<=10 plus ninf<=0), so
// softmax needs NO max pass: write exp(score) to out, atomically accumulate
// per-(b,p) denominators. Grid (pt, c, b) with b fastest (XCD locality).
// 128 threads, SC chunks of 256 n's, thread owns n = chunk*256 + 2t, +1.
// ---------------------------------------------------------------------------
#define PT2 10
#define SC 4
__global__ __launch_bounds__(128) void score_part_kernel(
        const float* __restrict__ aft,
        const float* __restrict__ nodesT,
        const float* __restrict__ cur_dist,
        const float* __restrict__ ninf,
        const float* __restrict__ log_scale,
        const float* __restrict__ dist_alpha,
        float* __restrict__ out,
        float* __restrict__ sums) {
    __shared__ float sa[PT2][D];
    __shared__ float red[2][PT2];
    const int t = threadIdx.x;
    const int wid = t >> 6;
    const int b    = blockIdx.x % B;
    const int rest = blockIdx.x / B;
    const int c    = rest % SC;
    const int pt   = rest / SC;
    const int p0 = pt * PT2;
    const float lsA = log_scale[0] * dist_alpha[0];

    // stage 10 aft rows (5 KB)
    for (int i = t; i < PT2 * D; i += 128) {
        sa[i >> 7][i & 127] = aft[((long)b * P + p0) * D + i];
    }
    __syncthreads();

    const int n0 = c * 256 + t * 2;
    const bool act = (n0 < N);
    const int ncl = act ? n0 : 0;
    const float* ntb = nodesT + (long)b * D * N;

    float2 acc[PT2];
    #pragma unroll
    for (int i = 0; i < PT2; ++i) acc[i] = make_float2(0.f, 0.f);

    float2 cx[4];
    #pragma unroll
    for (int ee = 0; ee < 4; ++ee)
        cx[ee] = *(const float2*)(ntb + (long)ee * N + ncl);

    for (int e0 = 0; e0 < D; e0 += 4) {
        float2 nx[4];
        if (e0 + 4 < D) {
            #pragma unroll
            for (int ee = 0; ee < 4; ++ee)
                nx[ee] = *(const float2*)(ntb + (long)(e0 + 4 + ee) * N + ncl);
        }
        #pragma unroll
        for (int i = 0; i < PT2; ++i) {
            float4 a4 = *(const float4*)(&sa[i][e0]);
            acc[i].x = fmaf(cx[0].x, a4.x, acc[i].x);
            acc[i].x = fmaf(cx[1].x, a4.y, acc[i].x);
            acc[i].x = fmaf(cx[2].x, a4.z, acc[i].x);
            acc[i].x = fmaf(cx[3].x, a4.w, acc[i].x);
            acc[i].y = fmaf(cx[0].y, a4.x, acc[i].y);
            acc[i].y = fmaf(cx[1].y, a4.y, acc[i].y);
            acc[i].y = fmaf(cx[2].y, a4.z, acc[i].y);
            acc[i].y = fmaf(cx[3].y, a4.w, acc[i].y);
        }
        #pragma unroll
        for (int ee = 0; ee < 4; ++ee) cx[ee] = nx[ee];
    }

    #pragma unroll
    for (int i = 0; i < PT2; ++i) {
        float2 ev = make_float2(0.f, 0.f);
        if (act) {
            long idx = ((long)b * P + p0 + i) * N + n0;
            float2 cd = *(const float2*)(cur_dist + idx);
            float2 nf = *(const float2*)(ninf + idx);
            float sx = fmaf(acc[i].x, SQRT_D_INV, -lsA * cd.x);
            float sy = fmaf(acc[i].y, SQRT_D_INV, -lsA * cd.y);
            float ax = fabsf(sx), ay = fabsf(sy);
            float rx = 1.f - 2.f / (__expf(2.f * ax) + 1.f);
            float ry = 1.f - 2.f / (__expf(2.f * ay) + 1.f);
            float scx = CLIPV * copysignf(rx, sx) + nf.x;
            float scy = CLIPV * copysignf(ry, sy) + nf.y;
            ev.x = __expf(scx);           // bounded: scx <= 10
            ev.y = __expf(scy);
            *(float2*)(out + idx) = ev;
        }
        // per-p partial denominator
        float s = ev.x + ev.y;
        #pragma unroll
        for (int o = 1; o < 64; o <<= 1) s += __shfl_xor(s, o, 64);
        if ((t & 63) == 0) red[wid][i] = s;
    }
    __syncthreads();
    if (t < PT2) {
        atomicAdd(&sums[b * P + p0 + t], red[0][t] + red[1][t]);
    }
}

// ---------------------------------------------------------------------------
// K4b: normalize — out[b,p,n] /= sums[b,p].  Block per (b,p) row.
// ---------------------------------------------------------------------------
__global__ __launch_bounds__(256) void normalize_kernel(
        float* __restrict__ out, const float* __restrict__ sums) {
    const int row = blockIdx.x;           // b*P + p
    const int t = threadIdx.x;
    const float inv = 1.0f / sums[row];
    float4* r = (float4*)(out + (long)row * N);
    if (t < N / 4) {
        float4 v = r[t];
        v.x *= inv; v.y *= inv; v.z *= inv; v.w *= inv;
        r[t] = v;
    }
}

// ---------------------------------------------------------------------------
extern "C" void kernel_launch(void* const* d_in, const int* in_sizes, int n_in,
                              void* d_out, int out_size, void* d_ws, size_t ws_size,
                              hipStream_t stream) {
    const float* nodes      = (const float*)d_in[0];
    const float* q1         = (const float*)d_in[1];
    const float* qlast      = (const float*)d_in[2];
    const float* cur_dist   = (const float*)d_in[3];
    const float* ninf       = (const float*)d_in[4];
    const float* log_scale  = (const float*)d_in[5];
    const float* Wqf        = (const float*)d_in[6];
    const float* Wql        = (const float*)d_in[7];
    const float* Wk         = (const float*)d_in[8];
    const float* Wv         = (const float*)d_in[9];
    const float* dist_alpha = (const float*)d_in[10];
    const float* aft_alpha  = (const float*)d_in[11];
    float* out = (float*)d_out;

    const long BND = (long)B * N * D;
    const long BPD = (long)B * P * D;
    const long W2  = (long)D * D;

    float* ws     = (float*)d_ws;
    float* ek     = ws;
    float* ekv    = ek + BND;
    float* qsig   = ekv + BND;
    float* aft    = qsig + BPD;
    float* wkT    = aft + BPD;
    float* wvT    = wkT + W2;
    float* wqfT   = wvT + W2;
    float* wqlT   = wqfT + W2;
    float* nodesT = wqlT + W2;
    float* sums   = nodesT + BND;        // B*P
    float* pnum   = sums + (long)B * P;

    long avail = (long)(ws_size / 4) - (3 * BND + 2 * BPD + 4 * W2 + (long)B * P);
    int NC = (int)(avail / (2 * BPD));
    if (NC < 1) NC = 1;
    if (NC > 12) NC = 12;
    int L = (N + NC - 1) / NC;
    NC = (N + L - 1) / L;
    float* pden = pnum + (long)NC * BPD;

    hipMemsetAsync(sums, 0, (size_t)B * P * sizeof(float), stream);
    prep_kernel<<<D + B * ((N + TT - 1) / TT), 256, 0, stream>>>(
        nodes, Wk, Wv, Wqf, Wql, wkT, wvT, wqfT, wqlT, nodesT);
    kv_kernel<<<(B * N) / R1, 256, 0, stream>>>(nodes, wkT, wvT, ek, ekv);
    q_kernel<<<(B * P) / R2, 256, 0, stream>>>(q1, qlast, wqfT, wqlT, qsig);
    aft_part_kernel<<<B * (P / PT) * NC, 128, 0, stream>>>(
        cur_dist, ninf, ek, ekv, log_scale, aft_alpha, pnum, pden, NC, L);
    aft_reduce_kernel<<<(int)(BPD / 256), 256, 0, stream>>>(pnum, pden, qsig, aft, NC);
    score_part_kernel<<<B * SC * (P / PT2), 128, 0, stream>>>(
        aft, nodesT, cur_dist, ninf, log_scale, dist_alpha, out, sums);
    normalize_kernel<<<B * P, 256, 0, stream>>>(out, sums);
}